// Round 10
// baseline (171.384 us; speedup 1.0000x reference)
//
#include <hip/hip_runtime.h>
#include <hip/hip_bf16.h>

#define N_SPK 2048
#define M_UTT 10
#define D_DIM 256
#define NM (N_SPK * M_UTT)   // 20480

typedef __attribute__((ext_vector_type(8))) short bf16x8_t;
typedef __attribute__((ext_vector_type(16))) float f32x16_t;

__device__ __forceinline__ short f2bf(float x) {
  __hip_bfloat16 h = __float2bfloat16(x);
  return *reinterpret_cast<short*>(&h);
}

// ---------------- K1: fused prep (round-7 proven version) ----------------
// One block per speaker n (2048 blocks x 256 threads, d = tid):
//  - centroid v = sum_m(e) / max(||sum||, 1e-11)  (== mean/max(||mean||,1e-12))
//  - Bf: centroid in 32x32x16 MFMA A-frag order (verified layout)
//  - embn: normalized rows in the SAME 32x32x16 frag order (B operand)
//  - dvals = cos(e_m, v); zero rowsum, zero out[0]
__global__ __launch_bounds__(256) void k_prep(const float* __restrict__ emb,
                                              __hip_bfloat16* __restrict__ Bf,
                                              __hip_bfloat16* __restrict__ embn,
                                              float* __restrict__ dvals,
                                              float* __restrict__ rowsum,
                                              float* __restrict__ out) {
  const int n = blockIdx.x, d = threadIdx.x;
  const int wid = d >> 6, lane = d & 63;
  const float* p = emb + (size_t)n * (M_UTT * D_DIM) + d;

  float e[M_UTT];
  float s = 0.f;
#pragma unroll
  for (int m = 0; m < M_UTT; ++m) { e[m] = p[m * D_DIM]; s += e[m]; }

  // centroid norm (block reduce of s^2)
  float ss = s * s;
#pragma unroll
  for (int o = 32; o >= 1; o >>= 1) ss += __shfl_xor(ss, o, 64);
  __shared__ float redc[4];
  if (lane == 0) redc[wid] = ss;
  __syncthreads();
  float tot = redc[0] + redc[1] + redc[2] + redc[3];
  float inv = 1.0f / fmaxf(sqrtf(tot), 1e-11f);
  float v = s * inv;

  // Bf fragment layout (verified rounds 2-8)
  int idx = (((n >> 5) * 16 + (d >> 4)) * 64 + ((d >> 3) & 1) * 32 + (n & 31)) * 8 + (d & 7);
  Bf[idx] = __float2bfloat16(v);

  // per-utterance ||e||^2 and e.v (block reduces)
  __shared__ float redm[M_UTT][2][4];
#pragma unroll
  for (int m = 0; m < M_UTT; ++m) {
    float a = e[m] * e[m], bb = e[m] * v;
#pragma unroll
    for (int o = 32; o >= 1; o >>= 1) {
      a += __shfl_xor(a, o, 64);
      bb += __shfl_xor(bb, o, 64);
    }
    if (lane == 0) { redm[m][0][wid] = a; redm[m][1][wid] = bb; }
  }
  __syncthreads();
  __shared__ float rnb[M_UTT];
  if (d < M_UTT) {
    float ssm = redm[d][0][0] + redm[d][0][1] + redm[d][0][2] + redm[d][0][3];
    float dtm = redm[d][1][0] + redm[d][1][1] + redm[d][1][2] + redm[d][1][3];
    float rn = 1.0f / fmaxf(sqrtf(ssm), 1e-12f);
    rnb[d] = rn;
    dvals[n * M_UTT + d] = dtm * rn;   // cos(e_m, centroid_n)
    rowsum[n * M_UTT + d] = 0.f;
  }
  if (n == 0 && d == 0) out[0] = 0.f;
  __syncthreads();

  short* eo = (short*)embn;
#pragma unroll
  for (int m = 0; m < M_UTT; ++m) {
    int row = n * M_UTT + m;
    int u = (((row >> 5) * 16 + (d >> 4)) * 64 + ((d >> 3) & 1) * 32 + (row & 31));
    eo[u * 8 + (d & 7)] = f2bf(e[m] * rnb[m]);
  }
}

// ---------------- K2: fused GEMM + exp row-sums (8-wave blocks) ----------------
// Round-7 math/per-wave code, but block = 8 waves = 512 emb rows x 128 cols at
// the SAME 64 KB LDS -> 2 blocks/CU = 16 waves/CU (4/SIMD) for latency hiding.
// Reverted round-8 regressions: breg loads issue BEFORE the vmcnt(0) drain
// (overlap with Bs staging); no diagonal extraction (dvals from k_prep).
// Bijective XCD remap: 640 blocks = 8 xcd x (16 colsplit x 5 rowq).
__global__ __launch_bounds__(512, 4) void k_gemm(const __hip_bfloat16* __restrict__ embn,
                                                 const __hip_bfloat16* __restrict__ Bf,
                                                 float* __restrict__ rowsum,
                                                 const float* __restrict__ wp) {
  __shared__ short Bs[128 * 256];  // 64 KB: 4 col-groups x 16 ks x 64 units x 8
  const float aw = fabsf(wp[0]);
  const int tid = threadIdx.x;
  const int lane = tid & 63, w = tid >> 6;          // w in [0,8)

  const int lid = blockIdx.x + 16 * blockIdx.y;     // 0..639 (dispatch order)
  const int xcd = lid & 7;
  const int slot = lid >> 3;                        // 0..79
  const int colsplit = slot & 15;                   // col-splits back-to-back
  const int rowg = xcd + 8 * (slot >> 4);           // 0..39, rowg == xcd (mod 8)

  const int row0 = rowg * 512 + w * 64;             // this wave's 64 emb rows
  const int Rb = rowg * 16 + w * 2;                 // 32-row block index

  // ---- stage this block's 128 centroid cols into LDS (linear copy) ----
  {
    const short* src = (const short*)Bf + (size_t)colsplit * 32768 + w * 512 + lane * 8;
#pragma unroll
    for (int it = 0; it < 8; ++it) {
      __builtin_amdgcn_global_load_lds(
          (const __attribute__((address_space(1))) void*)(src + it * 4096),
          (__attribute__((address_space(3))) void*)&Bs[it * 4096 + w * 512],
          16, 0, 0);
    }
  }

  // ---- breg: issued BEFORE the drain so the 32 loads overlap Bs staging ----
  const bf16x8_t* fp = (const bf16x8_t*)embn;
  bf16x8_t breg[2][16];
#pragma unroll
  for (int rg = 0; rg < 2; ++rg)
#pragma unroll
    for (int ks = 0; ks < 16; ++ks)
      breg[rg][ks] = fp[(size_t)((Rb + rg) * 16 + ks) * 64 + lane];

  asm volatile("s_waitcnt vmcnt(0)" ::: "memory");
  __syncthreads();

  float rowacc[2] = {0.f, 0.f};

#pragma unroll
  for (int c = 0; c < 2; ++c) {
    f32x16_t acc[2][2];
#pragma unroll
    for (int rg = 0; rg < 2; ++rg)
#pragma unroll
      for (int ci = 0; ci < 2; ++ci)
#pragma unroll
        for (int r = 0; r < 16; ++r) acc[rg][ci][r] = 0.f;

#pragma unroll
    for (int ks = 0; ks < 16; ++ks) {
      bf16x8_t c0 = *(const bf16x8_t*)&Bs[((2 * c) * 16 + ks) * 512 + lane * 8];
      bf16x8_t c1 = *(const bf16x8_t*)&Bs[((2 * c + 1) * 16 + ks) * 512 + lane * 8];
      acc[0][0] = __builtin_amdgcn_mfma_f32_32x32x16_bf16(c0, breg[0][ks], acc[0][0], 0, 0, 0);
      acc[0][1] = __builtin_amdgcn_mfma_f32_32x32x16_bf16(c1, breg[0][ks], acc[0][1], 0, 0, 0);
      acc[1][0] = __builtin_amdgcn_mfma_f32_32x32x16_bf16(c0, breg[1][ks], acc[1][0], 0, 0, 0);
      acc[1][1] = __builtin_amdgcn_mfma_f32_32x32x16_bf16(c1, breg[1][ks], acc[1][1], 0, 0, 0);
    }

    // exp-epilogue for this chunk's 64 cols (lane-local rows)
#pragma unroll
    for (int rg = 0; rg < 2; ++rg) {
      float s = 0.f;
#pragma unroll
      for (int ci = 0; ci < 2; ++ci)
#pragma unroll
        for (int r = 0; r < 16; ++r)
          s += __expf(fmaf(aw, acc[rg][ci][r], -aw));
      rowacc[rg] += s;
    }
  }

  // combine lh halves, one atomic per row
#pragma unroll
  for (int rg = 0; rg < 2; ++rg) {
    float s = rowacc[rg] + __shfl_xor(rowacc[rg], 32, 64);
    if (lane < 32) atomicAdd(&rowsum[row0 + rg * 32 + lane], s);
  }
}

// ---------------- K3: final reduction -> scalar loss ----------------
// out = sum_r [log(rowsum_r) + aw*(1 - dval_r)] / NM   (b cancels)
__global__ __launch_bounds__(256) void k_final(const float* __restrict__ rowsum,
                                               const float* __restrict__ dvals,
                                               const float* __restrict__ wp,
                                               float* __restrict__ out) {
  const float aw = fabsf(wp[0]);
  int base = blockIdx.x * 512 + threadIdx.x;
  float c = 0.f;
#pragma unroll
  for (int j = 0; j < 2; ++j) {
    int r = base + j * 256;
    c += logf(rowsum[r]) + aw * (1.0f - dvals[r]);
  }
#pragma unroll
  for (int o = 32; o >= 1; o >>= 1) c += __shfl_xor(c, o, 64);
  __shared__ float rs[4];
  int wid = threadIdx.x >> 6, lane = threadIdx.x & 63;
  if (lane == 0) rs[wid] = c;
  __syncthreads();
  if (threadIdx.x == 0)
    atomicAdd(out, (rs[0] + rs[1] + rs[2] + rs[3]) * (1.0f / (float)NM));
}

extern "C" void kernel_launch(void* const* d_in, const int* in_sizes, int n_in,
                              void* d_out, int out_size, void* d_ws, size_t ws_size,
                              hipStream_t stream) {
  const float* emb = (const float*)d_in[0];
  const float* wp  = (const float*)d_in[1];
  float* out = (float*)d_out;

  char* ws = (char*)d_ws;
  float* rowsum = (float*)(ws);                             // 80 KB @ 0
  float* dvals  = (float*)(ws + (128 << 10));               // 80 KB @ 128K
  __hip_bfloat16* Bf   = (__hip_bfloat16*)(ws + (1 << 20)); // 1 MB @ 1M (frag order)
  __hip_bfloat16* embn = (__hip_bfloat16*)(ws + (2 << 20)); // 10 MB @ 2M (frag order)

  k_prep<<<N_SPK, 256, 0, stream>>>(emb, Bf, embn, dvals, rowsum, out);
  k_gemm<<<dim3(16, NM / 512), 512, 0, stream>>>(embn, Bf, rowsum, wp);
  k_final<<<NM / 512, 256, 0, stream>>>(rowsum, dvals, wp, out);
}